// Round 9
// baseline (411.026 us; speedup 1.0000x reference)
//
#include <hip/hip_runtime.h>

#define N_NODES    100000
#define N_EDGES    1600000
#define DIM        64
#define NUM_GRAPHS 1000
#define SCAN_B     256
#define NBLK       ((N_NODES + SCAN_B - 1) / SCAN_B)   // 391
#define HIST_BLK   1563    // ceil((N_EDGES/4)/256)
#define CONV_BLK   3125    // (N_NODES*DIM/8)/256 exactly
#define FILL_SLICE 6400    // 256 slices x 6400 >= N_EDGES
#define NODES_PER_XCD (N_NODES / 8)   // 12500
#define PAD        72      // padded LDS row (bf16 units)

typedef __attribute__((ext_vector_type(8))) short bf16x8;
typedef __attribute__((ext_vector_type(4))) float f32x4;
typedef __attribute__((ext_vector_type(4))) int   i32x4;

// bf16 helpers (round-to-nearest-even)
__device__ __forceinline__ unsigned short f2bf(float f) {
    unsigned int b = __float_as_uint(f);
    b += 0x7FFFu + ((b >> 16) & 1u);
    return (unsigned short)(b >> 16);
}

// non-temporal loads via native clang vector types (builtin rejects HIP structs)
__device__ __forceinline__ int ntload_i(const int* p) {
    return __builtin_nontemporal_load(p);
}
__device__ __forceinline__ float ntload_f(const float* p) {
    return __builtin_nontemporal_load(p);
}
__device__ __forceinline__ int4 ntload_i4(const int* p) {
    i32x4 v = __builtin_nontemporal_load((const i32x4*)p);
    return make_int4(v.x, v.y, v.z, v.w);
}
__device__ __forceinline__ float4 ntload_f4(const float* p) {
    f32x4 v = __builtin_nontemporal_load((const f32x4*)p);
    return make_float4(v.x, v.y, v.z, v.w);
}

// ---------------------------------------------------------------------------
// Fused: dst-degree histogram (4 edges/thread) + x -> bf16 table conversion.
// x is streamed with non-temporal loads (read once, don't pollute L2).
// ---------------------------------------------------------------------------
__global__ __launch_bounds__(256) void prep(
    const int* __restrict__ ei, const float* __restrict__ x,
    int* __restrict__ deg, unsigned short* __restrict__ x16)
{
    int b = blockIdx.x;
    if (b < HIST_BLK) {
        int e4 = (b * 256 + threadIdx.x) * 4;
        if (e4 < N_EDGES) {
            int4 d = *(const int4*)(ei + N_EDGES + e4);
            atomicAdd(&deg[d.x], 1);
            atomicAdd(&deg[d.y], 1);
            atomicAdd(&deg[d.z], 1);
            atomicAdd(&deg[d.w], 1);
        }
    } else {
        int t = (b - HIST_BLK) * 256 + threadIdx.x;
        if (t < N_NODES * DIM / 8) {
            int base = t * 8;
            float4 f0 = ntload_f4(x + base);
            float4 f1 = ntload_f4(x + base + 4);
            uint4 o;
            o.x = (unsigned)f2bf(f0.x) | ((unsigned)f2bf(f0.y) << 16);
            o.y = (unsigned)f2bf(f0.z) | ((unsigned)f2bf(f0.w) << 16);
            o.z = (unsigned)f2bf(f1.x) | ((unsigned)f2bf(f1.y) << 16);
            o.w = (unsigned)f2bf(f1.z) | ((unsigned)f2bf(f1.w) << 16);
            *(uint4*)(x16 + base) = o;
        }
    }
}

// ---------------------------------------------------------------------------
// Scan: block-local exclusive scan, then per-block prefix fold
// ---------------------------------------------------------------------------
__global__ __launch_bounds__(SCAN_B) void scan1(
    const int* __restrict__ deg, int* __restrict__ rowptr, int* __restrict__ bsum)
{
    __shared__ int tmp[SCAN_B];
    int t = threadIdx.x;
    int i = blockIdx.x * SCAN_B + t;
    int v = (i < N_NODES) ? deg[i] : 0;
    tmp[t] = v;
    __syncthreads();
    for (int off = 1; off < SCAN_B; off <<= 1) {
        int u = (t >= off) ? tmp[t - off] : 0;
        __syncthreads();
        tmp[t] += u;
        __syncthreads();
    }
    if (i < N_NODES) rowptr[i] = tmp[t] - v;
    if (t == SCAN_B - 1) bsum[blockIdx.x] = tmp[t];
}

__global__ __launch_bounds__(SCAN_B) void scan23(
    int* __restrict__ rowptr, const int* __restrict__ bsum)
{
    __shared__ int red[SCAN_B];
    int t = threadIdx.x;
    int sum = 0;
    for (int i = t; i < blockIdx.x; i += SCAN_B) sum += bsum[i];
    red[t] = sum;
    __syncthreads();
    for (int off = SCAN_B / 2; off > 0; off >>= 1) {
        if (t < off) red[t] += red[t + off];
        __syncthreads();
    }
    int prefix = red[0];
    int i = blockIdx.x * SCAN_B + t;
    if (i < N_NODES) rowptr[i] += prefix;
    if (i == 0) rowptr[N_NODES] = N_EDGES;
}

// ---------------------------------------------------------------------------
// CSR fill, XCD-partitioned by dst range. Edge streams (ei, ea) use
// NON-TEMPORAL loads: R7 showed WRITE_SIZE 98.6 MB (8x payload) because the
// 6.4 MB/scan read stream evicted partially-filled dirty csr_e lines from
// L2 before their 8 records assembled. NT reads don't allocate in L2, so
// the ~1.6 MB/XCD dirty csr_e region stays resident and lines write back
// once, full.
// ---------------------------------------------------------------------------
__global__ __launch_bounds__(256) void csr_fill(
    const int* __restrict__ ei, const float* __restrict__ ea,
    const int* __restrict__ rowptr, int* __restrict__ cursor,
    int2* __restrict__ csr_e)
{
    int owner = blockIdx.x & 7;
    int slice = blockIdx.x >> 3;
    int lo = owner * NODES_PER_XCD;
    int hi = lo + NODES_PER_XCD;
    int base = slice * FILL_SLICE;
    int stop = min(base + FILL_SLICE, N_EDGES);
    for (int e = base + threadIdx.x * 4; e < stop; e += 256 * 4) {
        int4 d = ntload_i4(ei + N_EDGES + e);
        if (d.x >= lo && d.x < hi) {
            int p = rowptr[d.x] + atomicAdd(&cursor[d.x], 1);
            csr_e[p] = make_int2(ntload_i(ei + e + 0) << 4, __float_as_int(ntload_f(ea + e + 0)));
        }
        if (d.y >= lo && d.y < hi) {
            int p = rowptr[d.y] + atomicAdd(&cursor[d.y], 1);
            csr_e[p] = make_int2(ntload_i(ei + e + 1) << 4, __float_as_int(ntload_f(ea + e + 1)));
        }
        if (d.z >= lo && d.z < hi) {
            int p = rowptr[d.z] + atomicAdd(&cursor[d.z], 1);
            csr_e[p] = make_int2(ntload_i(ei + e + 2) << 4, __float_as_int(ntload_f(ea + e + 2)));
        }
        if (d.w >= lo && d.w < hi) {
            int p = rowptr[d.w] + atomicAdd(&cursor[d.w], 1);
            csr_e[p] = make_int2(ntload_i(ei + e + 3) << 4, __float_as_int(ntload_f(ea + e + 3)));
        }
    }
}

// ---------------------------------------------------------------------------
// Fused GINE layer with MFMA MLP.
// Phase 1 (gather): quarter-wave = node (32 nodes/block-iter), lane = 4 dims,
//   dwordx2 gather loads; agg -> h16 LDS tile (bf16, rows padded to 72).
// Phase 2 (MLP): wave w -> 16x16 C tile; mfma_f32_16x16x32_bf16, 2 K-steps
//   per matmul; weights staged transposed [n][k] bf16; bias in acc init.
// Verified layouts: A[m=lane&15][k=quad*8+j]; C/D col=lane&15 row=quad*4+reg.
// ---------------------------------------------------------------------------
template<bool SELF32>
__global__ __launch_bounds__(512, 8) void gine_mfma(
    const uint2* __restrict__ g2,      // [N*16] gather table rows (bf16x4 units)
    const float* __restrict__ self32,  // [N,64] fp32 self (SELF32 only)
    const int*   __restrict__ rowptr,
    const int2*  __restrict__ csr_e,   // {src*16, attr_bits}
    const float* __restrict__ We, const float* __restrict__ be,
    const float* __restrict__ Wa, const float* __restrict__ ba,
    const float* __restrict__ Wb, const float* __restrict__ bb,
    unsigned int* __restrict__ out16)  // bf16x2 rows
{
    __shared__ short sWat[64 * PAD];   // Wa^T: [n][k] bf16
    __shared__ short sWbt[64 * PAD];   // Wb^T
    __shared__ short h16[32 * PAD];    // MLP input tile (bf16)
    __shared__ short t16[32 * PAD];    // hidden tile (bf16)

    int t = threadIdx.x;
    for (int i = t; i < 4096; i += 512) {        // stage weights transposed
        int k = i >> 6, n = i & 63;
        sWat[n * PAD + k] = (short)f2bf(Wa[i]);
        sWbt[n * PAD + k] = (short)f2bf(Wb[i]);
    }
    int wave = t >> 6;            // 0..7
    int lane = t & 63;
    int quad = lane >> 4;         // 0..3
    int l15  = lane & 15;
    int slot = wave * 4 + quad;   // gather node slot 0..31
    int d0   = l15 * 4;           // this lane's 4 dims (gather phase)
    float4 wp = *(const float4*)(We + d0);
    float4 bp = *(const float4*)(be + d0);
    int mtile = wave & 1;         // MFMA role
    int ntile = wave >> 1;
    int col   = ntile * 16 + l15;
    int am    = mtile * 16 + l15; // A-fragment row
    float bav = ba[col], bbv = bb[col];
    __syncthreads();

    for (int base = blockIdx.x * 32; base < N_NODES; base += gridDim.x * 32) {
        // ---- phase 1: gather ----
        int  node  = base + slot;
        bool valid = node < N_NODES;
        int beg = 0, deg = 0;
        if (valid) { beg = rowptr[node]; deg = rowptr[node + 1] - beg; }
        int dm = deg;
        dm = max(dm, __shfl_xor(dm, 16));
        dm = max(dm, __shfl_xor(dm, 32));

        float4 agg = make_float4(0.f, 0.f, 0.f, 0.f);
        #define EDGE4(rr, uu, cond)                                              \
        {                                                                        \
            float s = (cond) ? 1.f : 0.f, av = __int_as_float(rr.y);             \
            float e0 = __uint_as_float(uu.x << 16);                              \
            float e1 = __uint_as_float(uu.x & 0xFFFF0000u);                      \
            float e2 = __uint_as_float(uu.y << 16);                              \
            float e3 = __uint_as_float(uu.y & 0xFFFF0000u);                      \
            agg.x = fmaf(s, fmaxf(e0 + fmaf(av, wp.x, bp.x), 0.f), agg.x);       \
            agg.y = fmaf(s, fmaxf(e1 + fmaf(av, wp.y, bp.y), 0.f), agg.y);       \
            agg.z = fmaf(s, fmaxf(e2 + fmaf(av, wp.z, bp.z), 0.f), agg.z);       \
            agg.w = fmaf(s, fmaxf(e3 + fmaf(av, wp.w, bp.w), 0.f), agg.w);       \
        }
        for (int j = 0; j < dm; j += 4) {
            int2 r0 = csr_e[beg + ((j + 0) < deg ? j + 0 : 0)];
            int2 r1 = csr_e[beg + ((j + 1) < deg ? j + 1 : 0)];
            int2 r2 = csr_e[beg + ((j + 2) < deg ? j + 2 : 0)];
            int2 r3 = csr_e[beg + ((j + 3) < deg ? j + 3 : 0)];
            uint2 u0 = g2[r0.x + l15];
            uint2 u1 = g2[r1.x + l15];
            uint2 u2 = g2[r2.x + l15];
            uint2 u3 = g2[r3.x + l15];
            EDGE4(r0, u0, (j + 0) < deg)
            EDGE4(r1, u1, (j + 1) < deg)
            EDGE4(r2, u2, (j + 2) < deg)
            EDGE4(r3, u3, (j + 3) < deg)
        }
        #undef EDGE4
        if (valid) {   // self term (eps = 0)
            if (SELF32) {
                float4 sv = *(const float4*)(self32 + (size_t)node * DIM + d0);
                agg.x += sv.x; agg.y += sv.y; agg.z += sv.z; agg.w += sv.w;
            } else {
                uint2 u = g2[node * 16 + l15];
                agg.x += __uint_as_float(u.x << 16);
                agg.y += __uint_as_float(u.x & 0xFFFF0000u);
                agg.z += __uint_as_float(u.y << 16);
                agg.w += __uint_as_float(u.y & 0xFFFF0000u);
            }
        }
        {
            unsigned lo = (unsigned)f2bf(agg.x) | ((unsigned)f2bf(agg.y) << 16);
            unsigned hi = (unsigned)f2bf(agg.z) | ((unsigned)f2bf(agg.w) << 16);
            *(uint2*)&h16[slot * PAD + d0] = make_uint2(lo, hi);
        }
        __syncthreads();

        // ---- matmul 1: t = relu(h @ Wa + ba) ----
        f32x4 acc = {bav, bav, bav, bav};
        #pragma unroll
        for (int s = 0; s < 2; ++s) {
            bf16x8 a = *(const bf16x8*)&h16[am * PAD + s * 32 + quad * 8];
            bf16x8 b = *(const bf16x8*)&sWat[col * PAD + s * 32 + quad * 8];
            acc = __builtin_amdgcn_mfma_f32_16x16x32_bf16(a, b, acc, 0, 0, 0);
        }
        #pragma unroll
        for (int r = 0; r < 4; ++r) {
            int row = mtile * 16 + quad * 4 + r;
            t16[row * PAD + col] = (short)f2bf(fmaxf(acc[r], 0.f));
        }
        __syncthreads();

        // ---- matmul 2: h_out = relu(t @ Wb + bb) ----
        f32x4 acc2 = {bbv, bbv, bbv, bbv};
        #pragma unroll
        for (int s = 0; s < 2; ++s) {
            bf16x8 a = *(const bf16x8*)&t16[am * PAD + s * 32 + quad * 8];
            bf16x8 b = *(const bf16x8*)&sWbt[col * PAD + s * 32 + quad * 8];
            acc2 = __builtin_amdgcn_mfma_f32_16x16x32_bf16(a, b, acc2, 0, 0, 0);
        }
        #pragma unroll
        for (int r = 0; r < 4; ++r) {
            int row = mtile * 16 + quad * 4 + r;
            h16[row * PAD + col] = (short)f2bf(fmaxf(acc2[r], 0.f));
        }
        __syncthreads();
        {
            int nn = t >> 4, dd = (t & 15) * 2;   // 32 nodes x 32 dwords
            if (base + nn < N_NODES) {
                uint2 v = *(const uint2*)&h16[nn * PAD + dd * 2];
                *(uint2*)&out16[(size_t)(base + nn) * 32 + dd] = v;
            }
        }
        __syncthreads();   // protect h16/t16 for next iteration
    }
}

// ---------------------------------------------------------------------------
// Fused pooling + classifier. Block = 4 graphs (wave per graph).
// ---------------------------------------------------------------------------
__device__ __forceinline__ int lbound(const int* __restrict__ a, int key) {
    int lo = 0, hi = N_NODES;
    while (lo < hi) {
        int mid = (lo + hi) >> 1;
        if (a[mid] < key) lo = mid + 1; else hi = mid;
    }
    return lo;
}

__global__ __launch_bounds__(256) void pool_cls(
    const unsigned int* __restrict__ B16b,  // [N*32] bf16x2 h2 rows
    const int* __restrict__ batch,
    const float* __restrict__ Wc1,  const float* __restrict__ bc1,
    const float* __restrict__ Wc2,  const float* __restrict__ bc2,
    float* __restrict__ out)
{
    __shared__ float sW[64 * 64];
    __shared__ float sp[4][64];

    int t = threadIdx.x;
    for (int i = t; i < 64 * 64; i += 256) sW[i] = Wc1[i];

    int nl   = t >> 6;           // wave = graph slot
    int lane = t & 63;
    int g    = blockIdx.x * 4 + nl;

    int p = lane & 31, h = lane >> 5;
    if (g < NUM_GRAPHS) {
        int s = lbound(batch, g);
        int e = lbound(batch, g + 1);
        float2 sum = make_float2(0.f, 0.f);
        for (int i = s + h; i < e; i += 2) {
            unsigned u = B16b[(size_t)i * 32 + p];
            sum.x += __uint_as_float(u << 16);
            sum.y += __uint_as_float(u & 0xFFFF0000u);
        }
        sum.x += __shfl_xor(sum.x, 32);
        sum.y += __shfl_xor(sum.y, 32);
        if (h == 0) {
            float inv = 1.f / (float)max(e - s, 1);
            sp[nl][2 * p]     = sum.x * inv;
            sp[nl][2 * p + 1] = sum.y * inv;
        }
    } else if (h == 0) {
        sp[nl][2 * p] = 0.f;
        sp[nl][2 * p + 1] = 0.f;
    }
    __syncthreads();

    float acc = bc1[lane];
    #pragma unroll
    for (int k = 0; k < 64; ++k)
        acc = fmaf(sp[nl][k], sW[k * 64 + lane], acc);
    float tv = fmaxf(acc, 0.f) * Wc2[lane];

    #pragma unroll
    for (int off = 32; off > 0; off >>= 1)
        tv += __shfl_down(tv, off);

    if (lane == 0 && g < NUM_GRAPHS) out[g] = tv + bc2[0];
}

extern "C" void kernel_launch(void* const* d_in, const int* in_sizes, int n_in,
                              void* d_out, int out_size, void* d_ws, size_t ws_size,
                              hipStream_t stream) {
    const float* x     = (const float*)d_in[0];
    const int*   ei    = (const int*)  d_in[1];
    const float* ea    = (const float*)d_in[2];
    const int*   batch = (const int*)  d_in[3];
    const float* W1a = (const float*)d_in[4];
    const float* b1a = (const float*)d_in[5];
    const float* W1b = (const float*)d_in[6];
    const float* b1b = (const float*)d_in[7];
    const float* We1 = (const float*)d_in[8];
    const float* be1 = (const float*)d_in[9];
    const float* W2a = (const float*)d_in[10];
    const float* b2a = (const float*)d_in[11];
    const float* W2b = (const float*)d_in[12];
    const float* b2b = (const float*)d_in[13];
    const float* We2 = (const float*)d_in[14];
    const float* be2 = (const float*)d_in[15];
    const float* Wc1 = (const float*)d_in[16];
    const float* bc1 = (const float*)d_in[17];
    const float* Wc2 = (const float*)d_in[18];
    const float* bc2 = (const float*)d_in[19];

    // workspace layout (16B-aligned arrays first)
    int2*           csr_e  = (int2*)d_ws;                            // [E]
    unsigned short* x16    = (unsigned short*)(csr_e + N_EDGES);     // [N*64]
    unsigned short* B16    = x16 + (size_t)N_NODES * DIM;            // [N*64] h1
    unsigned short* B16b   = B16 + (size_t)N_NODES * DIM;            // [N*64] h2
    int*            deg    = (int*)(B16b + (size_t)N_NODES * DIM);   // [N]
    int*            cursor = deg + N_NODES;                          // [N]
    int*            rowptr = cursor + N_NODES;                       // [N+2]
    int*            bsum   = rowptr + (N_NODES + 2);                 // [512]

    hipMemsetAsync(deg, 0, (size_t)2 * N_NODES * sizeof(int), stream);

    // ---- CSR build + bf16 table ----
    prep<<<HIST_BLK + CONV_BLK, 256, 0, stream>>>(ei, x, deg, x16);
    scan1<<<NBLK, SCAN_B, 0, stream>>>(deg, rowptr, bsum);
    scan23<<<NBLK, SCAN_B, 0, stream>>>(rowptr, bsum);
    csr_fill<<<2048, 256, 0, stream>>>(ei, ea, rowptr, cursor, csr_e);

    // ---- layer 1: gather x16, self fp32 x -> B16 (bf16) ----
    gine_mfma<true><<<1024, 512, 0, stream>>>(
        (const uint2*)x16, x, rowptr, csr_e,
        We1, be1, W1a, b1a, W1b, b1b, (unsigned int*)B16);

    // ---- layer 2: gather B16 -> B16b (bf16) ----
    gine_mfma<false><<<1024, 512, 0, stream>>>(
        (const uint2*)B16, nullptr, rowptr, csr_e,
        We2, be2, W2a, b2a, W2b, b2b, (unsigned int*)B16b);

    // ---- fused pooling + classifier ----
    pool_cls<<<(NUM_GRAPHS + 3) / 4, 256, 0, stream>>>(
        (const unsigned int*)B16b, batch, Wc1, bc1, Wc2, bc2, (float*)d_out);
}

// Round 10
// 301.173 us; speedup vs baseline: 1.3648x; 1.3648x over previous
//
#include <hip/hip_runtime.h>

#define N_NODES    100000
#define N_EDGES    1600000
#define DIM        64
#define NUM_GRAPHS 1000
#define CONV_BLK   3125    // (N_NODES*DIM/8)/256 exactly
#define PAD        72      // padded LDS row (bf16 units)

// ---- bucket-sort CSR parameters ----
#define SLICES     512
#define SLICE_E    3125    // N_EDGES / SLICES exact
#define NBUCK      782     // ceil(N_NODES / 128), bucket = dst >> 7
#define CAP4       3072    // max records per bucket (mean 2046, sd ~45)

typedef __attribute__((ext_vector_type(8))) short bf16x8;
typedef __attribute__((ext_vector_type(4))) float f32x4;

// bf16 helpers (round-to-nearest-even)
__device__ __forceinline__ unsigned short f2bf(float f) {
    unsigned int b = __float_as_uint(f);
    b += 0x7FFFu + ((b >> 16) & 1u);
    return (unsigned short)(b >> 16);
}

__device__ __forceinline__ float4 ntload_f4(const float* p) {
    f32x4 v = __builtin_nontemporal_load((const f32x4*)p);
    return make_float4(v.x, v.y, v.z, v.w);
}

// ---------------------------------------------------------------------------
// prep: role 1 (blocks < SLICES): per-slice bucket histogram of dst.
//       role 2: x -> bf16 table conversion (NT loads: read-once stream).
// ---------------------------------------------------------------------------
__global__ __launch_bounds__(256) void prep(
    const int* __restrict__ ei, const float* __restrict__ x,
    int* __restrict__ hist, int* __restrict__ bucketTotal,
    unsigned short* __restrict__ x16)
{
    __shared__ int lh[NBUCK];
    int blk = blockIdx.x, t = threadIdx.x;
    if (blk < SLICES) {
        for (int i = t; i < NBUCK; i += 256) lh[i] = 0;
        __syncthreads();
        const int* dsts = ei + N_EDGES + blk * SLICE_E;
        for (int k = t; k < SLICE_E; k += 256)
            atomicAdd(&lh[dsts[k] >> 7], 1);
        __syncthreads();
        for (int i = t; i < NBUCK; i += 256) {
            int h = lh[i];
            hist[blk * NBUCK + i] = h;
            if (h) atomicAdd(&bucketTotal[i], h);
        }
    } else {
        int tt = (blk - SLICES) * 256 + t;
        if (tt < N_NODES * DIM / 8) {
            int base = tt * 8;
            float4 f0 = ntload_f4(x + base);
            float4 f1 = ntload_f4(x + base + 4);
            uint4 o;
            o.x = (unsigned)f2bf(f0.x) | ((unsigned)f2bf(f0.y) << 16);
            o.y = (unsigned)f2bf(f0.z) | ((unsigned)f2bf(f0.w) << 16);
            o.z = (unsigned)f2bf(f1.x) | ((unsigned)f2bf(f1.y) << 16);
            o.w = (unsigned)f2bf(f1.z) | ((unsigned)f2bf(f1.w) << 16);
            *(uint4*)(x16 + base) = o;
        }
    }
}

// ---------------------------------------------------------------------------
// C2a: exclusive scan of bucketTotal -> bucketStart[0..NBUCK]
// ---------------------------------------------------------------------------
__global__ __launch_bounds__(1024) void csr_c2a(
    const int* __restrict__ bucketTotal, int* __restrict__ bucketStart)
{
    __shared__ int sc[1024];
    int t = threadIdx.x;
    int v = (t < NBUCK) ? bucketTotal[t] : 0;
    sc[t] = v;
    __syncthreads();
    for (int o = 1; o < 1024; o <<= 1) {
        int u = (t >= o) ? sc[t - o] : 0;
        __syncthreads();
        sc[t] += u;
        __syncthreads();
    }
    if (t < NBUCK) bucketStart[t] = sc[t] - v;
    if (t == NBUCK - 1) bucketStart[NBUCK] = sc[t];
}

// ---------------------------------------------------------------------------
// C2b: per-bucket exclusive scan over slices: off[b][s] = bucketStart[b] +
//      sum_{s'<s} hist[s'][b]  (where slice s's run for bucket b lands)
// ---------------------------------------------------------------------------
__global__ __launch_bounds__(512) void csr_c2b(
    const int* __restrict__ hist, const int* __restrict__ bucketStart,
    int* __restrict__ off)
{
    __shared__ int sc[512];
    int b = blockIdx.x, t = threadIdx.x;
    int v = hist[t * NBUCK + b];
    sc[t] = v;
    __syncthreads();
    for (int o = 1; o < 512; o <<= 1) {
        int u = (t >= o) ? sc[t - o] : 0;
        __syncthreads();
        sc[t] += u;
        __syncthreads();
    }
    off[b * SLICES + t] = bucketStart[b] + sc[t] - v;
}

// ---------------------------------------------------------------------------
// C3: per-slice LDS counting-sort by bucket; write tmp in (bucket, idx)
// order so consecutive lanes store consecutive addresses (coalesced runs).
// tmp record: .x = (dlocal << 17) | src   (dlocal = dst & 127, src < 2^17)
//             .y = edge-attr bits
// ---------------------------------------------------------------------------
__global__ __launch_bounds__(256) void csr_c3(
    const int* __restrict__ ei, const float* __restrict__ ea,
    const int* __restrict__ hist, const int* __restrict__ off,
    int2* __restrict__ tmp)
{
    __shared__ int2 staging[SLICE_E];             // 25000 B
    __shared__ int  lstart[NBUCK + 1];            // 3132
    __shared__ int  garr[NBUCK];                  // 3128
    __shared__ int  lcur[NBUCK];                  // 3128
    __shared__ unsigned short barr[SLICE_E];      // 6250
    __shared__ int  part[256];                    // 1024  (~41.7 KB total)

    int s = blockIdx.x, t = threadIdx.x;

    // load per-bucket counts (4 buckets/thread), block-scan partials
    int h[4];
    int mysum = 0;
    #pragma unroll
    for (int j = 0; j < 4; ++j) {
        int b = 4 * t + j;
        h[j] = (b < NBUCK) ? hist[s * NBUCK + b] : 0;
        mysum += h[j];
    }
    part[t] = mysum;
    for (int i = t; i < NBUCK; i += 256) {
        garr[i] = off[i * SLICES + s];
        lcur[i] = 0;
    }
    __syncthreads();
    for (int o = 1; o < 256; o <<= 1) {
        int u = (t >= o) ? part[t - o] : 0;
        __syncthreads();
        part[t] += u;
        __syncthreads();
    }
    int run = part[t] - mysum;                    // exclusive
    #pragma unroll
    for (int j = 0; j < 4; ++j) {
        int b = 4 * t + j;
        if (b < NBUCK) lstart[b] = run;
        run += h[j];
    }
    if (t == 0) lstart[NBUCK] = SLICE_E;
    __syncthreads();

    // bucket-of-slot map
    #pragma unroll
    for (int j = 0; j < 4; ++j) {
        int b = 4 * t + j;
        if (b < NBUCK)
            for (int i = lstart[b]; i < lstart[b + 1]; ++i)
                barr[i] = (unsigned short)b;
    }
    __syncthreads();

    // place records into bucket-sorted staging
    for (int k = t; k < SLICE_E; k += 256) {
        int e   = s * SLICE_E + k;
        int src = ei[e];
        int dst = ei[N_EDGES + e];
        float a = ea[e];
        int b   = dst >> 7;
        int p   = lstart[b] + atomicAdd(&lcur[b], 1);
        staging[p] = make_int2(((dst & 127) << 17) | src, __float_as_int(a));
    }
    __syncthreads();

    // coalesced write-out: consecutive lanes -> consecutive tmp addresses
    for (int i = t; i < SLICE_E; i += 256) {
        int b = barr[i];
        tmp[garr[b] + (i - lstart[b])] = staging[i];
    }
}

// ---------------------------------------------------------------------------
// C4: per-bucket exact counting-sort by node; sequential csr_e write-out;
// emits rowptr for the bucket's 128 nodes. Final record: {src<<4, attr}.
// ---------------------------------------------------------------------------
__global__ __launch_bounds__(256) void csr_c4(
    const int2* __restrict__ tmp, const int* __restrict__ bucketStart,
    int2* __restrict__ csr_e, int* __restrict__ rowptr)
{
    __shared__ int2 staging[CAP4];                // 24576 B
    __shared__ int  nh[128];
    __shared__ int  nscan[128];
    __shared__ int  ncur[128];

    int b = blockIdx.x, t = threadIdx.x;
    int lo = bucketStart[b], hi = bucketStart[b + 1];
    int cnt = hi - lo;
    int node0 = b << 7;
    int nn = min(128, N_NODES - node0);

    if (t < 128) { nh[t] = 0; ncur[t] = 0; }
    __syncthreads();

    int2 r[12];
    int nr = 0;
    for (int k = t; k < cnt; k += 256) {
        int2 v = tmp[lo + k];
        r[nr++] = v;
        atomicAdd(&nh[v.x >> 17], 1);
    }
    __syncthreads();

    if (t < 128) nscan[t] = nh[t];
    __syncthreads();
    for (int o = 1; o < 128; o <<= 1) {
        int u = (t >= o && t < 128) ? nscan[t - o] : 0;
        __syncthreads();
        if (t < 128) nscan[t] += u;
        __syncthreads();
    }
    if (t < 128) nscan[t] -= nh[t];               // exclusive
    __syncthreads();

    if (t < nn) rowptr[node0 + t] = lo + nscan[t];
    if (b == NBUCK - 1 && t == 0) rowptr[N_NODES] = N_EDGES;

    for (int k = 0; k < nr; ++k) {
        int dl = r[k].x >> 17;
        int p  = nscan[dl] + atomicAdd(&ncur[dl], 1);
        staging[p] = r[k];
    }
    __syncthreads();

    for (int i = t; i < cnt; i += 256) {
        int2 v = staging[i];
        csr_e[lo + i] = make_int2((v.x & 0x1FFFF) << 4, v.y);
    }
}

// ---------------------------------------------------------------------------
// Fused GINE layer with MFMA MLP (unchanged from R9).
// ---------------------------------------------------------------------------
template<bool SELF32>
__global__ __launch_bounds__(512, 8) void gine_mfma(
    const uint2* __restrict__ g2,      // [N*16] gather table rows (bf16x4 units)
    const float* __restrict__ self32,  // [N,64] fp32 self (SELF32 only)
    const int*   __restrict__ rowptr,
    const int2*  __restrict__ csr_e,   // {src*16, attr_bits}
    const float* __restrict__ We, const float* __restrict__ be,
    const float* __restrict__ Wa, const float* __restrict__ ba,
    const float* __restrict__ Wb, const float* __restrict__ bb,
    unsigned int* __restrict__ out16)  // bf16x2 rows
{
    __shared__ short sWat[64 * PAD];
    __shared__ short sWbt[64 * PAD];
    __shared__ short h16[32 * PAD];
    __shared__ short t16[32 * PAD];

    int t = threadIdx.x;
    for (int i = t; i < 4096; i += 512) {
        int k = i >> 6, n = i & 63;
        sWat[n * PAD + k] = (short)f2bf(Wa[i]);
        sWbt[n * PAD + k] = (short)f2bf(Wb[i]);
    }
    int wave = t >> 6;
    int lane = t & 63;
    int quad = lane >> 4;
    int l15  = lane & 15;
    int slot = wave * 4 + quad;
    int d0   = l15 * 4;
    float4 wp = *(const float4*)(We + d0);
    float4 bp = *(const float4*)(be + d0);
    int mtile = wave & 1;
    int ntile = wave >> 1;
    int col   = ntile * 16 + l15;
    int am    = mtile * 16 + l15;
    float bav = ba[col], bbv = bb[col];
    __syncthreads();

    for (int base = blockIdx.x * 32; base < N_NODES; base += gridDim.x * 32) {
        int  node  = base + slot;
        bool valid = node < N_NODES;
        int beg = 0, deg = 0;
        if (valid) { beg = rowptr[node]; deg = rowptr[node + 1] - beg; }
        int dm = deg;
        dm = max(dm, __shfl_xor(dm, 16));
        dm = max(dm, __shfl_xor(dm, 32));

        float4 agg = make_float4(0.f, 0.f, 0.f, 0.f);
        #define EDGE4(rr, uu, cond)                                              \
        {                                                                        \
            float s = (cond) ? 1.f : 0.f, av = __int_as_float(rr.y);             \
            float e0 = __uint_as_float(uu.x << 16);                              \
            float e1 = __uint_as_float(uu.x & 0xFFFF0000u);                      \
            float e2 = __uint_as_float(uu.y << 16);                              \
            float e3 = __uint_as_float(uu.y & 0xFFFF0000u);                      \
            agg.x = fmaf(s, fmaxf(e0 + fmaf(av, wp.x, bp.x), 0.f), agg.x);       \
            agg.y = fmaf(s, fmaxf(e1 + fmaf(av, wp.y, bp.y), 0.f), agg.y);       \
            agg.z = fmaf(s, fmaxf(e2 + fmaf(av, wp.z, bp.z), 0.f), agg.z);       \
            agg.w = fmaf(s, fmaxf(e3 + fmaf(av, wp.w, bp.w), 0.f), agg.w);       \
        }
        for (int j = 0; j < dm; j += 4) {
            int2 r0 = csr_e[beg + ((j + 0) < deg ? j + 0 : 0)];
            int2 r1 = csr_e[beg + ((j + 1) < deg ? j + 1 : 0)];
            int2 r2 = csr_e[beg + ((j + 2) < deg ? j + 2 : 0)];
            int2 r3 = csr_e[beg + ((j + 3) < deg ? j + 3 : 0)];
            uint2 u0 = g2[r0.x + l15];
            uint2 u1 = g2[r1.x + l15];
            uint2 u2 = g2[r2.x + l15];
            uint2 u3 = g2[r3.x + l15];
            EDGE4(r0, u0, (j + 0) < deg)
            EDGE4(r1, u1, (j + 1) < deg)
            EDGE4(r2, u2, (j + 2) < deg)
            EDGE4(r3, u3, (j + 3) < deg)
        }
        #undef EDGE4
        if (valid) {
            if (SELF32) {
                float4 sv = *(const float4*)(self32 + (size_t)node * DIM + d0);
                agg.x += sv.x; agg.y += sv.y; agg.z += sv.z; agg.w += sv.w;
            } else {
                uint2 u = g2[node * 16 + l15];
                agg.x += __uint_as_float(u.x << 16);
                agg.y += __uint_as_float(u.x & 0xFFFF0000u);
                agg.z += __uint_as_float(u.y << 16);
                agg.w += __uint_as_float(u.y & 0xFFFF0000u);
            }
        }
        {
            unsigned lo = (unsigned)f2bf(agg.x) | ((unsigned)f2bf(agg.y) << 16);
            unsigned hi = (unsigned)f2bf(agg.z) | ((unsigned)f2bf(agg.w) << 16);
            *(uint2*)&h16[slot * PAD + d0] = make_uint2(lo, hi);
        }
        __syncthreads();

        f32x4 acc = {bav, bav, bav, bav};
        #pragma unroll
        for (int s = 0; s < 2; ++s) {
            bf16x8 a = *(const bf16x8*)&h16[am * PAD + s * 32 + quad * 8];
            bf16x8 b = *(const bf16x8*)&sWat[col * PAD + s * 32 + quad * 8];
            acc = __builtin_amdgcn_mfma_f32_16x16x32_bf16(a, b, acc, 0, 0, 0);
        }
        #pragma unroll
        for (int r = 0; r < 4; ++r) {
            int row = mtile * 16 + quad * 4 + r;
            t16[row * PAD + col] = (short)f2bf(fmaxf(acc[r], 0.f));
        }
        __syncthreads();

        f32x4 acc2 = {bbv, bbv, bbv, bbv};
        #pragma unroll
        for (int s = 0; s < 2; ++s) {
            bf16x8 a = *(const bf16x8*)&t16[am * PAD + s * 32 + quad * 8];
            bf16x8 b = *(const bf16x8*)&sWbt[col * PAD + s * 32 + quad * 8];
            acc2 = __builtin_amdgcn_mfma_f32_16x16x32_bf16(a, b, acc2, 0, 0, 0);
        }
        #pragma unroll
        for (int r = 0; r < 4; ++r) {
            int row = mtile * 16 + quad * 4 + r;
            h16[row * PAD + col] = (short)f2bf(fmaxf(acc2[r], 0.f));
        }
        __syncthreads();
        {
            int nn = t >> 4, dd = (t & 15) * 2;
            if (base + nn < N_NODES) {
                uint2 v = *(const uint2*)&h16[nn * PAD + dd * 2];
                *(uint2*)&out16[(size_t)(base + nn) * 32 + dd] = v;
            }
        }
        __syncthreads();
    }
}

// ---------------------------------------------------------------------------
// Fused pooling + classifier (unchanged from R9).
// ---------------------------------------------------------------------------
__device__ __forceinline__ int lbound(const int* __restrict__ a, int key) {
    int lo = 0, hi = N_NODES;
    while (lo < hi) {
        int mid = (lo + hi) >> 1;
        if (a[mid] < key) lo = mid + 1; else hi = mid;
    }
    return lo;
}

__global__ __launch_bounds__(256) void pool_cls(
    const unsigned int* __restrict__ B16b,
    const int* __restrict__ batch,
    const float* __restrict__ Wc1,  const float* __restrict__ bc1,
    const float* __restrict__ Wc2,  const float* __restrict__ bc2,
    float* __restrict__ out)
{
    __shared__ float sW[64 * 64];
    __shared__ float sp[4][64];

    int t = threadIdx.x;
    for (int i = t; i < 64 * 64; i += 256) sW[i] = Wc1[i];

    int nl   = t >> 6;
    int lane = t & 63;
    int g    = blockIdx.x * 4 + nl;

    int p = lane & 31, h = lane >> 5;
    if (g < NUM_GRAPHS) {
        int s = lbound(batch, g);
        int e = lbound(batch, g + 1);
        float2 sum = make_float2(0.f, 0.f);
        for (int i = s + h; i < e; i += 2) {
            unsigned u = B16b[(size_t)i * 32 + p];
            sum.x += __uint_as_float(u << 16);
            sum.y += __uint_as_float(u & 0xFFFF0000u);
        }
        sum.x += __shfl_xor(sum.x, 32);
        sum.y += __shfl_xor(sum.y, 32);
        if (h == 0) {
            float inv = 1.f / (float)max(e - s, 1);
            sp[nl][2 * p]     = sum.x * inv;
            sp[nl][2 * p + 1] = sum.y * inv;
        }
    } else if (h == 0) {
        sp[nl][2 * p] = 0.f;
        sp[nl][2 * p + 1] = 0.f;
    }
    __syncthreads();

    float acc = bc1[lane];
    #pragma unroll
    for (int k = 0; k < 64; ++k)
        acc = fmaf(sp[nl][k], sW[k * 64 + lane], acc);
    float tv = fmaxf(acc, 0.f) * Wc2[lane];

    #pragma unroll
    for (int off = 32; off > 0; off >>= 1)
        tv += __shfl_down(tv, off);

    if (lane == 0 && g < NUM_GRAPHS) out[g] = tv + bc2[0];
}

extern "C" void kernel_launch(void* const* d_in, const int* in_sizes, int n_in,
                              void* d_out, int out_size, void* d_ws, size_t ws_size,
                              hipStream_t stream) {
    const float* x     = (const float*)d_in[0];
    const int*   ei    = (const int*)  d_in[1];
    const float* ea    = (const float*)d_in[2];
    const int*   batch = (const int*)  d_in[3];
    const float* W1a = (const float*)d_in[4];
    const float* b1a = (const float*)d_in[5];
    const float* W1b = (const float*)d_in[6];
    const float* b1b = (const float*)d_in[7];
    const float* We1 = (const float*)d_in[8];
    const float* be1 = (const float*)d_in[9];
    const float* W2a = (const float*)d_in[10];
    const float* b2a = (const float*)d_in[11];
    const float* W2b = (const float*)d_in[12];
    const float* b2b = (const float*)d_in[13];
    const float* We2 = (const float*)d_in[14];
    const float* be2 = (const float*)d_in[15];
    const float* Wc1 = (const float*)d_in[16];
    const float* bc1 = (const float*)d_in[17];
    const float* Wc2 = (const float*)d_in[18];
    const float* bc2 = (const float*)d_in[19];

    // workspace layout (~53 MB); tmp aliases B16b (dead until gine layer 2)
    int2*           csr_e  = (int2*)d_ws;                            // [E]
    unsigned short* x16    = (unsigned short*)(csr_e + N_EDGES);     // [N*64]
    unsigned short* B16    = x16 + (size_t)N_NODES * DIM;            // [N*64] h1
    unsigned short* B16b   = B16 + (size_t)N_NODES * DIM;            // [N*64] h2
    int2*           tmp    = (int2*)B16b;                            // [E] alias
    int*            hist   = (int*)(B16b + (size_t)N_NODES * DIM);   // [SLICES*NBUCK]
    int*            off    = hist + SLICES * NBUCK;                  // [NBUCK*SLICES]
    int*            bucketTotal = off + NBUCK * SLICES;              // [NBUCK]
    int*            bucketStart = bucketTotal + NBUCK;               // [NBUCK+1]
    int*            rowptr = bucketStart + (NBUCK + 1);              // [N+1]

    hipMemsetAsync(bucketTotal, 0, NBUCK * sizeof(int), stream);

    // ---- bucket-sort CSR build + bf16 table ----
    prep<<<SLICES + CONV_BLK, 256, 0, stream>>>(ei, x, hist, bucketTotal, x16);
    csr_c2a<<<1, 1024, 0, stream>>>(bucketTotal, bucketStart);
    csr_c2b<<<NBUCK, 512, 0, stream>>>(hist, bucketStart, off);
    csr_c3<<<SLICES, 256, 0, stream>>>(ei, ea, hist, off, tmp);
    csr_c4<<<NBUCK, 256, 0, stream>>>(tmp, bucketStart, csr_e, rowptr);

    // ---- layer 1: gather x16, self fp32 x -> B16 (bf16) ----
    gine_mfma<true><<<1024, 512, 0, stream>>>(
        (const uint2*)x16, x, rowptr, csr_e,
        We1, be1, W1a, b1a, W1b, b1b, (unsigned int*)B16);

    // ---- layer 2: gather B16 -> B16b (bf16) ----
    gine_mfma<false><<<1024, 512, 0, stream>>>(
        (const uint2*)B16, nullptr, rowptr, csr_e,
        We2, be2, W2a, b2a, W2b, b2b, (unsigned int*)B16b);

    // ---- fused pooling + classifier ----
    pool_cls<<<(NUM_GRAPHS + 3) / 4, 256, 0, stream>>>(
        (const unsigned int*)B16b, batch, Wc1, bc1, Wc2, bc2, (float*)d_out);
}